// Round 1
// baseline (2303.306 us; speedup 1.0000x reference)
//
#include <hip/hip_runtime.h>
#include <hip/hip_bf16.h>
#include <math.h>

// Sizes
#define QN 100
#define BN 8
#define HID 256
#define RN 800            // QN*BN flat rows, r = q*8 + b

// ---------------- t = output^T W  (per scale) ----------------
// t[r][c] = sum_o output[r][o] * w[o][c];  grid 100 blocks x 8 rows
__global__ __launch_bounds__(256) void k_t8(const float* __restrict__ outq,
                                            const float* __restrict__ w,
                                            float* __restrict__ t, int C) {
  __shared__ float orow[8][256];
  const int r0 = blockIdx.x * 8;
  for (int i = threadIdx.x; i < 8 * 256; i += 256)
    orow[i >> 8][i & 255] = outq[(size_t)r0 * 256 + i];
  __syncthreads();
  for (int c = threadIdx.x; c < C; c += 256) {
    float acc[8] = {0.f,0.f,0.f,0.f,0.f,0.f,0.f,0.f};
    for (int o = 0; o < 256; ++o) {
      float wv = w[(size_t)o * C + c];
      #pragma unroll
      for (int r = 0; r < 8; ++r) acc[r] = fmaf(orow[r][o], wv, acc[r]);
    }
    #pragma unroll
    for (int r = 0; r < 8; ++r) t[(size_t)(r0 + r) * C + c] = acc[r];
  }
}

// ---------------- scores = t . f  (per scale, per 4-batch group) ----------------
// tile: 16 q x 128 n, K = C staged in 32-chunks
#define QT 16
#define NTV 128
#define CT 32
__global__ __launch_bounds__(256) void k_score(const float* __restrict__ t,
                                               const float* __restrict__ f,
                                               float* __restrict__ sc,
                                               int C, int N, int b0) {
  const int q0 = blockIdx.x * QT;
  const int n0 = blockIdx.y * NTV;
  const int bz = blockIdx.z;          // 0..3 local batch in group
  const int b  = b0 + bz;
  __shared__ float tl[QT][CT];
  __shared__ float fl[CT][NTV];
  const int tn = threadIdx.x & 63;
  const int tq = threadIdx.x >> 6;    // 0..3
  float acc[4][2] = {};
  const float* fb = f + (size_t)b * C * N + n0;
  for (int c0 = 0; c0 < C; c0 += CT) {
    for (int i = threadIdx.x; i < QT * CT; i += 256) {
      int qq = i >> 5, cc = i & 31;
      int q = q0 + qq;
      tl[qq][cc] = (q < QN) ? t[(size_t)(q * 8 + b) * C + c0 + cc] : 0.f;
    }
    for (int i = threadIdx.x; i < CT * NTV; i += 256) {
      int cc = i >> 7, nn = i & 127;
      fl[cc][nn] = fb[(size_t)(c0 + cc) * N + nn];
    }
    __syncthreads();
    #pragma unroll
    for (int cc = 0; cc < CT; ++cc) {
      float fv0 = fl[cc][tn];
      float fv1 = fl[cc][tn + 64];
      #pragma unroll
      for (int j = 0; j < 4; ++j) {
        float tv = tl[tq + 4 * j][cc];
        acc[j][0] = fmaf(tv, fv0, acc[j][0]);
        acc[j][1] = fmaf(tv, fv1, acc[j][1]);
      }
    }
    __syncthreads();
  }
  #pragma unroll
  for (int j = 0; j < 4; ++j) {
    int q = q0 + tq + 4 * j;
    if (q < QN) {
      size_t row = (size_t)(bz * QN + q) * N + n0;
      sc[row + tn]      = acc[j][0];
      sc[row + tn + 64] = acc[j][1];
    }
  }
}

// ---------------- row softmax (in-place exp, store 1/l) ----------------
__global__ __launch_bounds__(256) void k_softmax(float* __restrict__ sc,
                                                 float* __restrict__ linv, int N) {
  const int row = blockIdx.x;          // 0..399 (bz*100+q)
  float* p = sc + (size_t)row * N;
  __shared__ float red[4];
  const int lane = threadIdx.x & 63, wid = threadIdx.x >> 6;
  float m = -INFINITY;
  for (int n = threadIdx.x; n < N; n += 256) m = fmaxf(m, p[n]);
  #pragma unroll
  for (int off = 32; off; off >>= 1) m = fmaxf(m, __shfl_down(m, off));
  if (lane == 0) red[wid] = m;
  __syncthreads();
  m = fmaxf(fmaxf(red[0], red[1]), fmaxf(red[2], red[3]));
  __syncthreads();
  float l = 0.f;
  for (int n = threadIdx.x; n < N; n += 256) {
    float e = __expf(p[n] - m);
    p[n] = e;
    l += e;
  }
  #pragma unroll
  for (int off = 32; off; off >>= 1) l += __shfl_down(l, off);
  if (lane == 0) red[wid] = l;
  __syncthreads();
  if (threadIdx.x == 0) linv[row] = 1.f / (red[0] + red[1] + red[2] + red[3]);
}

// ---------------- u += attn . f  (split-K over n, atomics) ----------------
#define CTT 128
#define NTK 32
__global__ __launch_bounds__(256) void k_pv(const float* __restrict__ sc,
                                            const float* __restrict__ linv,
                                            const float* __restrict__ f,
                                            float* __restrict__ u,
                                            int C, int N, int b0, int kc) {
  const int q0 = blockIdx.x * QT;
  const int c0 = blockIdx.y * CTT;
  const int bz = blockIdx.z / kc;
  const int k  = blockIdx.z % kc;
  const int b  = b0 + bz;
  const int chunk = N / kc;
  const int ns = k * chunk;
  __shared__ float pl[QT][NTK];
  __shared__ float fl[CTT][NTK + 1];
  const int tc = threadIdx.x & 63;
  const int tq = threadIdx.x >> 6;
  float acc[4][2] = {};
  const float* fb = f + (size_t)b * C * N;
  for (int n0 = ns; n0 < ns + chunk; n0 += NTK) {
    for (int i = threadIdx.x; i < QT * NTK; i += 256) {
      int qq = i >> 5, nn = i & 31;
      int q = q0 + qq;
      pl[qq][nn] = (q < QN) ? sc[(size_t)(bz * QN + q) * N + n0 + nn] * linv[bz * QN + q]
                            : 0.f;
    }
    for (int i = threadIdx.x; i < CTT * NTK; i += 256) {
      int cc = i >> 5, nn = i & 31;
      fl[cc][nn] = fb[(size_t)(c0 + cc) * N + n0 + nn];
    }
    __syncthreads();
    #pragma unroll
    for (int nn = 0; nn < NTK; ++nn) {
      float fv0 = fl[tc][nn];
      float fv1 = fl[tc + 64][nn];
      #pragma unroll
      for (int j = 0; j < 4; ++j) {
        float pv = pl[tq + 4 * j][nn];
        acc[j][0] = fmaf(pv, fv0, acc[j][0]);
        acc[j][1] = fmaf(pv, fv1, acc[j][1]);
      }
    }
    __syncthreads();
  }
  #pragma unroll
  for (int j = 0; j < 4; ++j) {
    int q = q0 + tq + 4 * j;
    if (q < QN) {
      atomicAdd(&u[(size_t)(q * 8 + b) * C + c0 + tc],      acc[j][0]);
      atomicAdd(&u[(size_t)(q * 8 + b) * C + c0 + tc + 64], acc[j][1]);
    }
  }
}

// ---------------- queries = W u + b -> aq columns ----------------
__global__ __launch_bounds__(256) void k_queries(const float* __restrict__ u,
                                                 const float* __restrict__ w,
                                                 const float* __restrict__ bias,
                                                 float* __restrict__ aq,
                                                 int C, int soff) {
  const int r0 = blockIdx.x * 8;
  __shared__ float urt[8][16];
  __shared__ float wt[256][17];
  const int o = threadIdx.x;
  float acc[8] = {0.f,0.f,0.f,0.f,0.f,0.f,0.f,0.f};
  for (int c0 = 0; c0 < C; c0 += 16) {
    __syncthreads();
    for (int i = threadIdx.x; i < 256 * 16; i += 256) {
      int oo = i >> 4, cc = i & 15;
      wt[oo][cc] = w[(size_t)oo * C + c0 + cc];
    }
    if (threadIdx.x < 128) {
      int r = threadIdx.x >> 4, cc = threadIdx.x & 15;
      urt[r][cc] = u[(size_t)(r0 + r) * C + c0 + cc];
    }
    __syncthreads();
    #pragma unroll
    for (int cc = 0; cc < 16; ++cc) {
      float wv = wt[o][cc];
      #pragma unroll
      for (int r = 0; r < 8; ++r) acc[r] = fmaf(wv, urt[r][cc], acc[r]);
    }
  }
  float bv = bias[o];
  #pragma unroll
  for (int r = 0; r < 8; ++r)
    aq[(size_t)(r0 + r) * 768 + soff + o] = acc[r] + bv;
}

// ---------------- fused tail: agg MLP -> LN -> proj MLP ----------------
__device__ void dense256(const float* in, int ID, const float* __restrict__ w,
                         const float* __restrict__ bias, float* out, bool relu,
                         float (*wt)[17]) {
  const int o = threadIdx.x;
  float acc[8] = {0.f,0.f,0.f,0.f,0.f,0.f,0.f,0.f};
  for (int c0 = 0; c0 < ID; c0 += 16) {
    __syncthreads();
    for (int i = threadIdx.x; i < 256 * 16; i += 256) {
      int oo = i >> 4, cc = i & 15;
      wt[oo][cc] = w[(size_t)oo * ID + c0 + cc];
    }
    __syncthreads();
    #pragma unroll
    for (int cc = 0; cc < 16; ++cc) {
      float wv = wt[o][cc];
      #pragma unroll
      for (int r = 0; r < 8; ++r) acc[r] = fmaf(wv, in[r * ID + c0 + cc], acc[r]);
    }
  }
  __syncthreads();
  float bv = bias[o];
  #pragma unroll
  for (int r = 0; r < 8; ++r) {
    float v = acc[r] + bv;
    out[r * 256 + o] = relu ? fmaxf(v, 0.f) : v;
  }
}

__global__ __launch_bounds__(256) void k_tail(
    const float* __restrict__ aq,
    const float* __restrict__ aw1, const float* __restrict__ ab1,
    const float* __restrict__ aw2, const float* __restrict__ ab2,
    const float* __restrict__ lng, const float* __restrict__ lnb,
    const float* __restrict__ pw1, const float* __restrict__ pb1,
    const float* __restrict__ pw2, const float* __restrict__ pb2,
    const float* __restrict__ pw3, const float* __restrict__ pb3,
    float* __restrict__ out) {
  const int r0 = blockIdx.x * 8;
  __shared__ float bufA[8 * 768];
  __shared__ float bufB[8 * 256];
  __shared__ float bufC[8 * 256];
  __shared__ float wt[256][17];
  __shared__ float mu[8], iv[8];
  for (int i = threadIdx.x; i < 8 * 768; i += 256)
    bufA[i] = aq[(size_t)r0 * 768 + i];
  dense256(bufA, 768, aw1, ab1, bufB, true, wt);   // h
  __syncthreads();
  dense256(bufB, 256, aw2, ab2, bufC, false, wt);  // y
  __syncthreads();
  if (threadIdx.x < 8) {
    int r = threadIdx.x;
    float s = 0.f, ss = 0.f;
    for (int o2 = 0; o2 < 256; ++o2) {
      float v = bufC[r * 256 + o2];
      s += v; ss += v * v;
    }
    float m = s * (1.f / 256.f);
    float var = ss * (1.f / 256.f) - m * m;
    mu[r] = m;
    iv[r] = 1.f / sqrtf(var + 1e-5f);
  }
  __syncthreads();
  {
    const int o = threadIdx.x;
    float g = lng[o], bb = lnb[o];
    #pragma unroll
    for (int r = 0; r < 8; ++r)
      bufB[r * 256 + o] = (bufC[r * 256 + o] - mu[r]) * iv[r] * g + bb;
  }
  __syncthreads();
  dense256(bufB, 256, pw1, pb1, bufC, true, wt);
  __syncthreads();
  dense256(bufC, 256, pw2, pb2, bufA, true, wt);   // reuse bufA as [8][256]
  __syncthreads();
  dense256(bufA, 256, pw3, pb3, bufB, false, wt);
  __syncthreads();
  const int o = threadIdx.x;
  #pragma unroll
  for (int r = 0; r < 8; ++r)
    out[(size_t)(r0 + r) * 256 + o] = bufB[r * 256 + o];
}

extern "C" void kernel_launch(void* const* d_in, const int* in_sizes, int n_in,
                              void* d_out, int out_size, void* d_ws, size_t ws_size,
                              hipStream_t stream) {
  (void)in_sizes; (void)n_in; (void)out_size; (void)ws_size;
  const float* outq = (const float*)d_in[0];
  const float* f0 = (const float*)d_in[1];
  const float* f1 = (const float*)d_in[2];
  const float* f2 = (const float*)d_in[3];
  const float* w0 = (const float*)d_in[5];
  const float* b0 = (const float*)d_in[6];
  const float* w1 = (const float*)d_in[7];
  const float* b1 = (const float*)d_in[8];
  const float* w2 = (const float*)d_in[9];
  const float* b2 = (const float*)d_in[10];
  const float* lng = (const float*)d_in[11];
  const float* lnb = (const float*)d_in[12];
  const float* aw1 = (const float*)d_in[13];
  const float* ab1 = (const float*)d_in[14];
  const float* aw2 = (const float*)d_in[15];
  const float* ab2 = (const float*)d_in[16];
  const float* pw1 = (const float*)d_in[17];
  const float* pb1 = (const float*)d_in[18];
  const float* pw2 = (const float*)d_in[19];
  const float* pb2 = (const float*)d_in[20];
  const float* pw3 = (const float*)d_in[21];
  const float* pb3 = (const float*)d_in[22];

  float* ws = (float*)d_ws;
  float* t0 = ws;                         // 800*256
  float* t1 = t0 + 204800;                // 800*512
  float* t2 = t1 + 409600;                // 800*1024
  float* u0 = t2 + 819200;                // 800*256
  float* u1 = u0 + 204800;                // 800*512
  float* u2 = u1 + 409600;                // 800*1024
  float* aq = u2 + 819200;                // 800*768
  float* linv = aq + 614400;              // 400 (+pad)
  float* sc = linv + 512;                 // 400*16384 max

  // zero the u accumulators (re-poisoned to 0xAA before every timed call)
  hipMemsetAsync(u0, 0, (size_t)(204800 + 409600 + 819200) * sizeof(float), stream);

  k_t8<<<100, 256, 0, stream>>>(outq, w0, t0, 256);
  k_t8<<<100, 256, 0, stream>>>(outq, w1, t1, 512);
  k_t8<<<100, 256, 0, stream>>>(outq, w2, t2, 1024);

  struct Sc { const float* f; const float* w; const float* b; float* t; float* u;
              int C, N, kc, soff; };
  Sc scs[3] = {
    {f0, w0, b0, t0, u0, 256, 16384, 16, 0},
    {f1, w1, b1, t1, u1, 512, 4096, 8, 256},
    {f2, w2, b2, t2, u2, 1024, 1024, 4, 512},
  };
  for (int s = 0; s < 3; ++s) {
    for (int g = 0; g < 2; ++g) {
      int b0g = g * 4;
      dim3 gs(7, scs[s].N / NTV, 4);
      k_score<<<gs, 256, 0, stream>>>(scs[s].t, scs[s].f, sc, scs[s].C, scs[s].N, b0g);
      k_softmax<<<400, 256, 0, stream>>>(sc, linv, scs[s].N);
      dim3 gp(7, scs[s].C / CTT, 4 * scs[s].kc);
      k_pv<<<gp, 256, 0, stream>>>(sc, linv, scs[s].f, scs[s].u,
                                   scs[s].C, scs[s].N, b0g, scs[s].kc);
    }
  }
  for (int s = 0; s < 3; ++s)
    k_queries<<<100, 256, 0, stream>>>(scs[s].u, scs[s].w, scs[s].b, aq,
                                       scs[s].C, scs[s].soff);
  k_tail<<<100, 256, 0, stream>>>(aq, aw1, ab1, aw2, ab2, lng, lnb,
                                  pw1, pb1, pw2, pb2, pw3, pb3, (float*)d_out);
}

// Round 2
// 1054.669 us; speedup vs baseline: 2.1839x; 2.1839x over previous
//
#include <hip/hip_runtime.h>
#include <hip/hip_bf16.h>
#include <math.h>

typedef float f32x4 __attribute__((ext_vector_type(4)));
typedef _Float16 half8 __attribute__((ext_vector_type(8)));
typedef _Float16 half4 __attribute__((ext_vector_type(4)));

__device__ __forceinline__ half8 h8z() {
  half8 v;
  #pragma unroll
  for (int j = 0; j < 8; ++j) v[j] = (_Float16)0.f;
  return v;
}

__device__ __forceinline__ half8 cvt8(f32x4 a, f32x4 b) {
  half8 v;
  #pragma unroll
  for (int j = 0; j < 4; ++j) { v[j] = (_Float16)a[j]; v[j + 4] = (_Float16)b[j]; }
  return v;
}

// ---------------- t = output^T W, written as fp16 hi/lo ----------------
__global__ __launch_bounds__(256) void k_t8(const float* __restrict__ outq,
                                            const float* __restrict__ w,
                                            _Float16* __restrict__ th,
                                            _Float16* __restrict__ tl, int C) {
  __shared__ float orow[8][256];
  const int r0 = blockIdx.x * 8;
  const int c = blockIdx.y * 256 + threadIdx.x;
  for (int i = threadIdx.x; i < 512; i += 256)
    ((f32x4*)orow)[i] = ((const f32x4*)(outq + (size_t)r0 * 256))[i];
  __syncthreads();
  float acc[8] = {};
  #pragma unroll 4
  for (int o = 0; o < 256; ++o) {
    float wv = w[(size_t)o * C + c];
    #pragma unroll
    for (int r = 0; r < 8; ++r) acc[r] = fmaf(orow[r][o], wv, acc[r]);
  }
  #pragma unroll
  for (int r = 0; r < 8; ++r) {
    float v = acc[r];
    _Float16 h = (_Float16)v;
    size_t idx = (size_t)(r0 + r) * C + c;
    th[idx] = h;
    tl[idx] = (_Float16)(v - (float)h);
  }
}

// ---------------- scores = t . f  (MFMA, split hi/lo on t) ----------------
// block: NW waves, each wave covers [112 q][32 n]; all q-tiles per block.
template<int C, int N, int NW>
__global__ __launch_bounds__(NW * 64) void k_score(
    const _Float16* __restrict__ th, const _Float16* __restrict__ tl,
    const float* __restrict__ f, float* __restrict__ sc, int b0) {
  const int w = threadIdx.x >> 6;
  const int l = threadIdx.x & 63;
  const int ln = l & 15, kg = l >> 4;
  const int bz = blockIdx.y, b = b0 + bz;
  const int nw = blockIdx.x * (NW * 32) + w * 32;
  const float* fb = f + (size_t)b * C * N;
  f32x4 acc[7][2] = {};
  for (int c0 = 0; c0 < C; c0 += 32) {
    half8 ah[7], al[7];
    #pragma unroll
    for (int qt = 0; qt < 7; ++qt) {
      int q = qt * 16 + ln;
      int qc = q < 100 ? q : 99;
      size_t off = ((size_t)qc * 8 + b) * C + c0 + kg * 8;
      half8 vh = *(const half8*)(th + off);
      half8 vl = *(const half8*)(tl + off);
      if (q < 100) { ah[qt] = vh; al[qt] = vl; }
      else { ah[qt] = h8z(); al[qt] = h8z(); }
    }
    #pragma unroll
    for (int s = 0; s < 2; ++s) {
      const float* fp = fb + (size_t)(c0 + kg * 8) * N + nw + s * 16 + ln;
      half8 bh;
      #pragma unroll
      for (int j = 0; j < 8; ++j) bh[j] = (_Float16)fp[(size_t)j * N];
      #pragma unroll
      for (int qt = 0; qt < 7; ++qt) {
        acc[qt][s] = __builtin_amdgcn_mfma_f32_16x16x32_f16(ah[qt], bh, acc[qt][s], 0, 0, 0);
        acc[qt][s] = __builtin_amdgcn_mfma_f32_16x16x32_f16(al[qt], bh, acc[qt][s], 0, 0, 0);
      }
    }
  }
  // D layout: row = kg*4 + r, col = ln
  #pragma unroll
  for (int qt = 0; qt < 7; ++qt)
    #pragma unroll
    for (int s = 0; s < 2; ++s)
      #pragma unroll
      for (int r = 0; r < 4; ++r) {
        int q = qt * 16 + kg * 4 + r;
        if (q < 100)
          sc[((size_t)bz * 100 + q) * N + nw + s * 16 + ln] = acc[qt][s][r];
      }
}

// ---------------- row softmax: fp32 in, normalized fp16 out ----------------
template<int N>
__global__ __launch_bounds__(256) void k_softmax(const float* __restrict__ sc,
                                                 _Float16* __restrict__ p) {
  const int row = blockIdx.y * 100 + blockIdx.x;
  const float* s = sc + (size_t)row * N;
  _Float16* pr = p + (size_t)row * N;
  __shared__ float red[4];
  const int lane = threadIdx.x & 63, wid = threadIdx.x >> 6;
  float m = -1e30f;
  for (int n = threadIdx.x * 4; n < N; n += 1024) {
    f32x4 v = *(const f32x4*)(s + n);
    m = fmaxf(fmaxf(fmaxf(v[0], v[1]), fmaxf(v[2], v[3])), m);
  }
  #pragma unroll
  for (int off = 32; off; off >>= 1) m = fmaxf(m, __shfl_down(m, off));
  if (lane == 0) red[wid] = m;
  __syncthreads();
  m = fmaxf(fmaxf(red[0], red[1]), fmaxf(red[2], red[3]));
  __syncthreads();
  float lsum = 0.f;
  for (int n = threadIdx.x * 4; n < N; n += 1024) {
    f32x4 v = *(const f32x4*)(s + n);
    half4 h;
    #pragma unroll
    for (int j = 0; j < 4; ++j) {
      float e = __expf(v[j] - m);
      h[j] = (_Float16)e;
      lsum += e;
    }
    *(half4*)(pr + n) = h;
  }
  #pragma unroll
  for (int off = 32; off; off >>= 1) lsum += __shfl_down(lsum, off);
  if (lane == 0) red[wid] = lsum;
  __syncthreads();
  const float linv = 1.f / (red[0] + red[1] + red[2] + red[3]);
  for (int n = threadIdx.x * 4; n < N; n += 1024) {
    half4 h = *(half4*)(pr + n);
    #pragma unroll
    for (int j = 0; j < 4; ++j) h[j] = (_Float16)((float)h[j] * linv);
    *(half4*)(pr + n) = h;
  }
}

// ---------------- u += p . f^T  (MFMA fp16, split-K atomics) ----------------
template<int C, int N, int KC, int CH>
__global__ __launch_bounds__(512) void k_pv(const _Float16* __restrict__ p,
                                            const float* __restrict__ f,
                                            float* __restrict__ u, int b0) {
  constexpr int WC = CH / 8;      // cols per wave
  constexpr int SC = WC / 16;     // 16-col subtiles per wave
  constexpr int CHUNK = N / KC;
  static_assert(CHUNK % 32 == 0, "chunk");
  const int w = threadIdx.x >> 6, l = threadIdx.x & 63;
  const int ln = l & 15, kg = l >> 4;
  const int k = blockIdx.x, cb = blockIdx.y * CH, bz = blockIdx.z, b = b0 + bz;
  const int cw = cb + w * WC;
  const float* fb = f + (size_t)b * C * N;
  const _Float16* pb = p + (size_t)bz * 100 * N;
  f32x4 acc[7][SC] = {};
  for (int n0 = k * CHUNK; n0 < (k + 1) * CHUNK; n0 += 32) {
    half8 a[7];
    #pragma unroll
    for (int qt = 0; qt < 7; ++qt) {
      int q = qt * 16 + ln;
      int qc = q < 100 ? q : 99;
      half8 v = *(const half8*)(pb + (size_t)qc * N + n0 + kg * 8);
      a[qt] = (q < 100) ? v : h8z();
    }
    #pragma unroll
    for (int s = 0; s < SC; ++s) {
      const float* fp = fb + (size_t)(cw + s * 16 + ln) * N + n0 + kg * 8;
      half8 bh = cvt8(*(const f32x4*)fp, *(const f32x4*)(fp + 4));
      #pragma unroll
      for (int qt = 0; qt < 7; ++qt)
        acc[qt][s] = __builtin_amdgcn_mfma_f32_16x16x32_f16(a[qt], bh, acc[qt][s], 0, 0, 0);
    }
  }
  #pragma unroll
  for (int qt = 0; qt < 7; ++qt)
    #pragma unroll
    for (int s = 0; s < SC; ++s)
      #pragma unroll
      for (int r = 0; r < 4; ++r) {
        int q = qt * 16 + kg * 4 + r;
        if (q < 100)
          atomicAdd(&u[(size_t)(q * 8 + b) * C + cw + s * 16 + ln], acc[qt][s][r]);
      }
}

// ---------------- MFMA dense layer: act(LDS fp16 hi/lo) x W^T + b ----------
// act rows 8..15 must be zero. 4 waves, 64 cols each, 256 outputs.
template<bool GOUT, bool RELU>
__device__ __forceinline__ void dense_mfma(const _Float16* ah, const _Float16* al,
                                           int AP, int ID,
                                           const float* __restrict__ wgt,
                                           const float* __restrict__ bias,
                                           float* gout, int GS,
                                           _Float16* oh, _Float16* ol, int OP) {
  const int w = threadIdx.x >> 6, l = threadIdx.x & 63;
  const int ln = l & 15, kg = l >> 4;
  const int cw = w * 64;
  f32x4 acc[4] = {};
  for (int k0 = 0; k0 < ID; k0 += 32) {
    const int ao = ln * AP + k0 + kg * 8;
    half8 va = *(const half8*)(ah + ao);
    half8 vb = *(const half8*)(al + ao);
    #pragma unroll
    for (int s = 0; s < 4; ++s) {
      const float* wp = wgt + (size_t)(cw + s * 16 + ln) * ID + k0 + kg * 8;
      half8 bh = cvt8(*(const f32x4*)wp, *(const f32x4*)(wp + 4));
      acc[s] = __builtin_amdgcn_mfma_f32_16x16x32_f16(va, bh, acc[s], 0, 0, 0);
      acc[s] = __builtin_amdgcn_mfma_f32_16x16x32_f16(vb, bh, acc[s], 0, 0, 0);
    }
  }
  #pragma unroll
  for (int s = 0; s < 4; ++s) {
    const int col = cw + s * 16 + ln;
    const float bv = bias[col];
    #pragma unroll
    for (int r = 0; r < 4; ++r) {
      const int row = kg * 4 + r;
      if (row < 8) {
        float v = acc[s][r] + bv;
        if (RELU) v = fmaxf(v, 0.f);
        if (GOUT) {
          gout[(size_t)row * GS + col] = v;
        } else {
          _Float16 h = (_Float16)v;
          oh[row * OP + col] = h;
          ol[row * OP + col] = (_Float16)(v - (float)h);
        }
      }
    }
  }
}

// ---------------- queries = W u + b -> aq columns (MFMA) ----------------
__global__ __launch_bounds__(256) void k_queries(const float* __restrict__ u,
                                                 const float* __restrict__ wgt,
                                                 const float* __restrict__ bias,
                                                 float* __restrict__ aq,
                                                 int C, int soff, int lc) {
  __shared__ _Float16 uh[16 * 1032];
  __shared__ _Float16 ul[16 * 1032];
  const int r0b = blockIdx.x * 8;
  const int AP = C + 8;
  for (int i = threadIdx.x; i < 8 * C; i += 256) {
    int r = i >> lc, c = i & (C - 1);
    float v = u[(size_t)(r0b + r) * C + c];
    _Float16 h = (_Float16)v;
    uh[r * AP + c] = h;
    ul[r * AP + c] = (_Float16)(v - (float)h);
  }
  for (int i = threadIdx.x; i < 8 * C; i += 256) {
    int r = 8 + (i >> lc), c = i & (C - 1);
    uh[r * AP + c] = (_Float16)0.f;
    ul[r * AP + c] = (_Float16)0.f;
  }
  __syncthreads();
  dense_mfma<true, false>(uh, ul, AP, C, wgt, bias,
                          aq + (size_t)r0b * 768 + soff, 768, nullptr, nullptr, 0);
}

// ---------------- fused tail: agg MLP -> LN -> proj MLP (MFMA) ----------------
__global__ __launch_bounds__(256) void k_tail(const float* __restrict__ aq,
    const float* __restrict__ aw1, const float* __restrict__ ab1,
    const float* __restrict__ aw2, const float* __restrict__ ab2,
    const float* __restrict__ lng, const float* __restrict__ lnb,
    const float* __restrict__ pw1, const float* __restrict__ pb1,
    const float* __restrict__ pw2, const float* __restrict__ pb2,
    const float* __restrict__ pw3, const float* __restrict__ pb3,
    float* __restrict__ out) {
  __shared__ _Float16 Ah[16 * 776], Al[16 * 776];
  __shared__ _Float16 Bh[16 * 264], Bl[16 * 264];
  __shared__ _Float16 Ch[16 * 264], Cl[16 * 264];
  __shared__ float mu[8], iv[8];
  const int r0b = blockIdx.x * 8;
  for (int i = threadIdx.x; i < 8 * 768; i += 256) {
    int r = i / 768, c = i - r * 768;
    float v = aq[(size_t)r0b * 768 + i];
    _Float16 h = (_Float16)v;
    Ah[r * 776 + c] = h;
    Al[r * 776 + c] = (_Float16)(v - (float)h);
  }
  for (int i = threadIdx.x; i < 8 * 776; i += 256) {
    Ah[8 * 776 + i] = (_Float16)0.f;
    Al[8 * 776 + i] = (_Float16)0.f;
  }
  for (int i = threadIdx.x; i < 8 * 264; i += 256) {
    Bh[8 * 264 + i] = (_Float16)0.f; Bl[8 * 264 + i] = (_Float16)0.f;
    Ch[8 * 264 + i] = (_Float16)0.f; Cl[8 * 264 + i] = (_Float16)0.f;
  }
  __syncthreads();
  dense_mfma<false, true >(Ah, Al, 776, 768, aw1, ab1, nullptr, 0, Bh, Bl, 264);
  __syncthreads();
  dense_mfma<false, false>(Bh, Bl, 264, 256, aw2, ab2, nullptr, 0, Ch, Cl, 264);
  __syncthreads();
  {  // LayerNorm stats over C rows 0..7
    const int wv = threadIdx.x >> 6, l = threadIdx.x & 63;
    for (int r = wv; r < 8; r += 4) {
      float s = 0.f, ss = 0.f;
      for (int j = l; j < 256; j += 64) {
        float v = (float)Ch[r * 264 + j] + (float)Cl[r * 264 + j];
        s += v;
        ss = fmaf(v, v, ss);
      }
      #pragma unroll
      for (int off = 32; off; off >>= 1) {
        s += __shfl_down(s, off);
        ss += __shfl_down(ss, off);
      }
      if (l == 0) {
        float mm = s * (1.f / 256.f);
        mu[r] = mm;
        iv[r] = rsqrtf(ss * (1.f / 256.f) - mm * mm + 1e-5f);
      }
    }
  }
  __syncthreads();
  {
    const int o = threadIdx.x;
    const float g = lng[o], bb = lnb[o];
    #pragma unroll
    for (int r = 0; r < 8; ++r) {
      float v = (float)Ch[r * 264 + o] + (float)Cl[r * 264 + o];
      float z = (v - mu[r]) * iv[r] * g + bb;
      _Float16 h = (_Float16)z;
      Bh[r * 264 + o] = h;
      Bl[r * 264 + o] = (_Float16)(z - (float)h);
    }
  }
  __syncthreads();
  dense_mfma<false, true >(Bh, Bl, 264, 256, pw1, pb1, nullptr, 0, Ch, Cl, 264);
  __syncthreads();
  dense_mfma<false, true >(Ch, Cl, 264, 256, pw2, pb2, nullptr, 0, Bh, Bl, 264);
  __syncthreads();
  dense_mfma<true, false>(Bh, Bl, 264, 256, pw3, pb3, out + (size_t)r0b * 256, 256,
                          nullptr, nullptr, 0);
}

extern "C" void kernel_launch(void* const* d_in, const int* in_sizes, int n_in,
                              void* d_out, int out_size, void* d_ws, size_t ws_size,
                              hipStream_t stream) {
  (void)in_sizes; (void)n_in; (void)out_size;
  const float* outq = (const float*)d_in[0];
  const float* f0 = (const float*)d_in[1];
  const float* f1 = (const float*)d_in[2];
  const float* f2 = (const float*)d_in[3];
  const float* w0 = (const float*)d_in[5];
  const float* bc0 = (const float*)d_in[6];
  const float* w1 = (const float*)d_in[7];
  const float* bc1 = (const float*)d_in[8];
  const float* w2 = (const float*)d_in[9];
  const float* bc2 = (const float*)d_in[10];
  const float* lng = (const float*)d_in[11];
  const float* lnb = (const float*)d_in[12];
  const float* aw1 = (const float*)d_in[13];
  const float* ab1 = (const float*)d_in[14];
  const float* aw2 = (const float*)d_in[15];
  const float* ab2 = (const float*)d_in[16];
  const float* pw1 = (const float*)d_in[17];
  const float* pb1 = (const float*)d_in[18];
  const float* pw2 = (const float*)d_in[19];
  const float* pb2 = (const float*)d_in[20];
  const float* pw3 = (const float*)d_in[21];
  const float* pb3 = (const float*)d_in[22];

  char* W = (char*)d_ws;
  float* u0 = (float*)(W);                   //  800*256*4  = 819200
  float* u1 = (float*)(W + 819200);          //  800*512*4  = 1638400
  float* u2 = (float*)(W + 2457600);         //  800*1024*4 = 3276800
  float* aqp = (float*)(W + 5734400);        //  800*768*4  = 2457600
  _Float16* th0 = (_Float16*)(W + 8192000);  //  409600
  _Float16* tl0 = (_Float16*)(W + 8601600);  //  409600
  _Float16* th1 = (_Float16*)(W + 9011200);  //  819200
  _Float16* tl1 = (_Float16*)(W + 9830400);  //  819200
  _Float16* th2 = (_Float16*)(W + 10649600); // 1638400
  _Float16* tl2 = (_Float16*)(W + 12288000); // 1638400
  const size_t fixed = 13926400;
  const size_t perg = 9830400;  // sc (fp32) + p (fp16) per batch in group
  int g = 1;
  if (ws_size >= fixed + 8 * perg) g = 8;
  else if (ws_size >= fixed + 4 * perg) g = 4;
  else if (ws_size >= fixed + 2 * perg) g = 2;
  float* sc = (float*)(W + fixed);
  _Float16* pp = (_Float16*)(W + fixed + (size_t)g * 6553600);

  hipMemsetAsync(u0, 0, 5734400, stream);  // zero u0,u1,u2 (contiguous)

  k_t8<<<dim3(100, 1), 256, 0, stream>>>(outq, w0, th0, tl0, 256);
  k_t8<<<dim3(100, 2), 256, 0, stream>>>(outq, w1, th1, tl1, 512);
  k_t8<<<dim3(100, 4), 256, 0, stream>>>(outq, w2, th2, tl2, 1024);

  for (int b0g = 0; b0g < 8; b0g += g) {
    k_score<256, 16384, 8><<<dim3(64, g), 512, 0, stream>>>(th0, tl0, f0, sc, b0g);
    k_softmax<16384><<<dim3(100, g), 256, 0, stream>>>(sc, pp);
    k_pv<256, 16384, 32, 256><<<dim3(32, 1, g), 512, 0, stream>>>(pp, f0, u0, b0g);
  }
  for (int b0g = 0; b0g < 8; b0g += g) {
    k_score<512, 4096, 8><<<dim3(16, g), 512, 0, stream>>>(th1, tl1, f1, sc, b0g);
    k_softmax<4096><<<dim3(100, g), 256, 0, stream>>>(sc, pp);
    k_pv<512, 4096, 16, 512><<<dim3(16, 1, g), 512, 0, stream>>>(pp, f1, u1, b0g);
  }
  for (int b0g = 0; b0g < 8; b0g += g) {
    k_score<1024, 1024, 2><<<dim3(16, g), 128, 0, stream>>>(th2, tl2, f2, sc, b0g);
    k_softmax<1024><<<dim3(100, g), 256, 0, stream>>>(sc, pp);
    k_pv<1024, 1024, 8, 512><<<dim3(8, 2, g), 512, 0, stream>>>(pp, f2, u2, b0g);
  }

  k_queries<<<100, 256, 0, stream>>>(u0, w0, bc0, aqp, 256, 0, 8);
  k_queries<<<100, 256, 0, stream>>>(u1, w1, bc1, aqp, 512, 256, 9);
  k_queries<<<100, 256, 0, stream>>>(u2, w2, bc2, aqp, 1024, 512, 10);
  k_tail<<<100, 256, 0, stream>>>(aqp, aw1, ab1, aw2, ab2, lng, lnb,
                                  pw1, pb1, pw2, pb2, pw3, pb3, (float*)d_out);
}